// Round 5
// baseline (360.639 us; speedup 1.0000x reference)
//
#include <hip/hip_runtime.h>

#define BB 64
#define PP 8732
#define NOBJ 16
#define NC 81
#define THRESH 0.5f
#define NEGPOS 3
#define NCHUNK 4
#define CHUNK (PP / NCHUNK)   // 2183

#define TK_THREADS 512
#define TK_KEYS 18            // 17*512 = 8704; threads 0..27 hold an 18th key

__device__ __forceinline__ float smooth_l1(float x) {
    float ax = fabsf(x);
    return (ax < 1.0f) ? 0.5f * x * x : ax - 0.5f;
}

// ---------- Kernel 1: fused match (single dispatch, block-local only) ----------
// Grid (NCHUNK, BB) x 256. Pass 1: EVERY block scans ALL priors for the
// per-truth best (redundant x4 compute ~4us, but no cross-block deps and no
// g_best global round-trip; all 4 chunk-blocks of a batch compute identical
// s_bpi deterministically). Pass 2: own chunk -> conf_t + loc loss.
// Per-chunk partials written with plain stores (no zero-init / no atomics).
// Zeroes accum/done_cnt for later dispatches (stream-ordered).
__global__ __launch_bounds__(256) void k_match(
    const float* __restrict__ loc_data, const float* __restrict__ priors,
    const float* __restrict__ targets,
    unsigned char* __restrict__ conf_t,
    int* __restrict__ num_pos_part, float* __restrict__ lloss_part,
    int* __restrict__ done_cnt, double* __restrict__ accum)
{
    const int chunk = blockIdx.x;
    const int b = blockIdx.y;
    const int tid = threadIdx.x;

    __shared__ float s_tx1[NOBJ], s_ty1[NOBJ], s_tx2[NOBJ], s_ty2[NOBJ];
    __shared__ float s_lab[NOBJ], s_area[NOBJ];
    __shared__ unsigned long long s_best[NOBJ];
    __shared__ int s_bpi[NOBJ];

    if (tid < NOBJ) {
        const float* t = targets + ((size_t)b * NOBJ + tid) * 5;
        float x1 = t[0], y1 = t[1], x2 = t[2], y2 = t[3];
        s_tx1[tid] = x1; s_ty1[tid] = y1; s_tx2[tid] = x2; s_ty2[tid] = y2;
        s_lab[tid] = t[4];
        s_area[tid] = (x2 - x1) * (y2 - y1);
        s_best[tid] = 0ull;
    }
    if (chunk == 0 && b == 0 && tid == 0) {
        accum[0] = 0.0; accum[1] = 0.0; done_cnt[0] = 0;
    }
    __syncthreads();

    // ---- pass 1: per-truth best prior over ALL priors (block-local) ----
    unsigned long long best[NOBJ];
    #pragma unroll
    for (int t = 0; t < NOBJ; ++t) best[t] = 0ull;

    for (int p = tid; p < PP; p += 256) {
        float4 pr = ((const float4*)priors)[p];
        float px1 = pr.x - pr.z * 0.5f, py1 = pr.y - pr.w * 0.5f;
        float px2 = pr.x + pr.z * 0.5f, py2 = pr.y + pr.w * 0.5f;
        float pa = (px2 - px1) * (py2 - py1);
        unsigned revp = 0xFFFFFFFFu - (unsigned)p;   // tie -> smaller p wins
        #pragma unroll
        for (int t = 0; t < NOBJ; ++t) {
            float ix1 = fmaxf(s_tx1[t], px1), iy1 = fmaxf(s_ty1[t], py1);
            float ix2 = fminf(s_tx2[t], px2), iy2 = fminf(s_ty2[t], py2);
            float iw = fmaxf(ix2 - ix1, 0.f), ih = fmaxf(iy2 - iy1, 0.f);
            float inter = iw * ih;
            float iou = inter / (s_area[t] + pa - inter);
            unsigned long long key =
                ((unsigned long long)__float_as_uint(iou) << 32) | revp;
            if (key > best[t]) best[t] = key;
        }
    }
    #pragma unroll
    for (int t = 0; t < NOBJ; ++t) {
        unsigned long long v = best[t];
        for (int o = 32; o > 0; o >>= 1) {
            unsigned long long w = __shfl_down(v, o);
            if (w > v) v = w;
        }
        if ((tid & 63) == 0) atomicMax(&s_best[t], v);
    }
    __syncthreads();
    if (tid < NOBJ)
        s_bpi[tid] = (int)(0xFFFFFFFFu - (unsigned)(s_best[tid] & 0xFFFFFFFFull));
    __syncthreads();

    // ---- pass 2: own chunk -> conf_t + loc loss ----
    int n_pos = 0;
    float lloss = 0.f;
    const int p0 = chunk * CHUNK, p1 = p0 + CHUNK;
    for (int p = p0 + tid; p < p1; p += 256) {
        float4 pr = ((const float4*)priors)[p];
        float px1 = pr.x - pr.z * 0.5f, py1 = pr.y - pr.w * 0.5f;
        float px2 = pr.x + pr.z * 0.5f, py2 = pr.y + pr.w * 0.5f;
        float pa = (px2 - px1) * (py2 - py1);
        float bt_ov = -1.f;
        int bt_idx = 0;
        #pragma unroll
        for (int t = 0; t < NOBJ; ++t) {
            float ix1 = fmaxf(s_tx1[t], px1), iy1 = fmaxf(s_ty1[t], py1);
            float ix2 = fminf(s_tx2[t], px2), iy2 = fminf(s_ty2[t], py2);
            float iw = fmaxf(ix2 - ix1, 0.f), ih = fmaxf(iy2 - iy1, 0.f);
            float inter = iw * ih;
            float iou = inter / (s_area[t] + pa - inter);
            if (iou > bt_ov) { bt_ov = iou; bt_idx = t; }  // strict >: first-max
        }
        #pragma unroll
        for (int i = 0; i < NOBJ; ++i)           // last-wins scatter override
            if (s_bpi[i] == p) { bt_idx = i; bt_ov = 2.0f; }

        int c = (bt_ov < THRESH) ? 0 : ((int)s_lab[bt_idx] + 1);
        conf_t[(size_t)b * PP + p] = (unsigned char)c;

        if (c > 0) {
            n_pos++;
            float mx1 = s_tx1[bt_idx], my1 = s_ty1[bt_idx];
            float mx2 = s_tx2[bt_idx], my2 = s_ty2[bt_idx];
            float gcx = ((mx1 + mx2) * 0.5f - pr.x) / (0.1f * pr.z);
            float gcy = ((my1 + my2) * 0.5f - pr.y) / (0.1f * pr.w);
            float gw = logf((mx2 - mx1) / pr.z) / 0.2f;
            float gh = logf((my2 - my1) / pr.w) / 0.2f;
            float4 ld = ((const float4*)loc_data)[(size_t)b * PP + p];
            lloss += smooth_l1(ld.x - gcx) + smooth_l1(ld.y - gcy) +
                     smooth_l1(ld.z - gw) + smooth_l1(ld.w - gh);
        }
    }

    for (int o = 32; o > 0; o >>= 1) {
        n_pos += __shfl_down(n_pos, o);
        lloss += __shfl_down(lloss, o);
    }
    __shared__ int s_np[4];
    __shared__ float s_ll[4];
    if ((tid & 63) == 0) { s_np[tid >> 6] = n_pos; s_ll[tid >> 6] = lloss; }
    __syncthreads();
    if (tid == 0) {
        num_pos_part[b * NCHUNK + chunk] = s_np[0] + s_np[1] + s_np[2] + s_np[3];
        lloss_part[b * NCHUNK + chunk] = s_ll[0] + s_ll[1] + s_ll[2] + s_ll[3];
    }
}

// ---------- Kernel 2: conf loss, double-buffered LDS, octet-per-row ----------
// (byte-for-byte the R2-verified kernel)
__global__ __launch_bounds__(256) void k_conf(
    const float* __restrict__ conf_data, const unsigned char* __restrict__ conf_t,
    float* __restrict__ lcm, double* __restrict__ accum)
{
    __shared__ float4 s_buf4[2][648];        // 2 x 32 rows x 81 floats
    const int tid = threadIdx.x;
    const int r = tid >> 3;                  // row in half-chunk (0..31)
    const int s = tid & 7;                   // octet segment (0..7)
    const int seg_start = s * 10;
    const int seg_len = (s == 7) ? 11 : 10;  // 7*10 + 11 = 81
    const int base_row = blockIdx.x * 256;   // 2183*256 == BB*PP exactly
    const float4* g4base = (const float4*)conf_data;

    float4 t0, t1, t2;
    {
        const float4* g4 = g4base + (size_t)base_row * NC / 4;
        t0 = g4[tid]; t1 = g4[tid + 256];
        if (tid < 136) t2 = g4[tid + 512];
    }

    float posl = 0.f;
    for (int h = 0; h < 8; ++h) {
        float4* buf = s_buf4[h & 1];
        buf[tid] = t0; buf[tid + 256] = t1;
        if (tid < 136) buf[tid + 512] = t2;
        if (h + 1 < 8) {                     // issue next loads (latency hidden)
            const float4* g4 = g4base + (size_t)(base_row + (h + 1) * 32) * NC / 4;
            t0 = g4[tid]; t1 = g4[tid + 256];
            if (tid < 136) t2 = g4[tid + 512];
        }
        __syncthreads();                     // single barrier per half-chunk

        const float* myrow = (const float*)buf + r * NC;
        float v[11];
        #pragma unroll
        for (int j = 0; j < 11; ++j) v[j] = myrow[seg_start + j];

        float m = -1e30f;
        #pragma unroll
        for (int j = 0; j < 11; ++j) m = fmaxf(m, (j < seg_len) ? v[j] : -1e30f);
        m = fmaxf(m, __shfl_xor(m, 1));
        m = fmaxf(m, __shfl_xor(m, 2));
        m = fmaxf(m, __shfl_xor(m, 4));
        float e = 0.f;
        #pragma unroll
        for (int j = 0; j < 11; ++j) e += (j < seg_len) ? __expf(v[j] - m) : 0.f;
        e += __shfl_xor(e, 1);
        e += __shfl_xor(e, 2);
        e += __shfl_xor(e, 4);

        if (s == 0) {
            int row = base_row + h * 32 + r;
            int c = (int)conf_t[row];
            float lse = m + __logf(e);
            float lc = lse - myrow[c];
            bool pos = c > 0;
            lcm[row] = pos ? 0.f : lc;
            if (pos) posl += lc;
        }
    }
    for (int o = 32; o > 0; o >>= 1) posl += __shfl_down(posl, o);
    __shared__ float s_w[4];
    if ((tid & 63) == 0) s_w[tid >> 6] = posl;
    __syncthreads();
    if (tid == 0)
        atomicAdd(&accum[1], (double)(s_w[0] + s_w[1] + s_w[2] + s_w[3]));
}

// ---------- Kernel 3: per-batch top-k via radix-256 select + finalize ----------
// (R2-verified structure; num_pos/lloss now come from plain-store partials)
__global__ __launch_bounds__(TK_THREADS) void k_topk(
    const float* __restrict__ lcm, const int* __restrict__ num_pos_part,
    const float* __restrict__ lloss_part,
    double* __restrict__ accum, int* __restrict__ done_cnt,
    float* __restrict__ out)
{
    const int b = blockIdx.x, tid = threadIdx.x;
    unsigned key[TK_KEYS];
    #pragma unroll
    for (int j = 0; j < TK_KEYS; ++j) {
        int i = tid + j * TK_THREADS;
        key[j] = (i < PP) ? __float_as_uint(lcm[(size_t)b * PP + i]) : 0u;
    }
    __shared__ int s_hist[256];
    __shared__ int s_vk[2];                  // {selected byte, next kk}
    int np = num_pos_part[b * NCHUNK + 0] + num_pos_part[b * NCHUNK + 1] +
             num_pos_part[b * NCHUNK + 2] + num_pos_part[b * NCHUNK + 3];
    int k = NEGPOS * np;
    if (k > PP - 1) k = PP - 1;

    unsigned P = 0;
    int kk = k;
    #pragma unroll
    for (int rd = 0; rd < 4; ++rd) {
        const int shift = 24 - 8 * rd;
        if (tid < 256) s_hist[tid] = 0;
        __syncthreads();
        const unsigned hi_mask = (rd == 0) ? 0u : (0xFFFFFFFFu << (shift + 8));
        #pragma unroll
        for (int j = 0; j < TK_KEYS; ++j) {
            int i = tid + j * TK_THREADS;
            if (i < PP && (((key[j] ^ P) & hi_mask) == 0u))
                atomicAdd(&s_hist[(key[j] >> shift) & 255], 1);
        }
        __syncthreads();
        if (tid < 64) {                      // wave 0: suffix-scan 256 bins
            int h0 = s_hist[4 * tid + 0], h1 = s_hist[4 * tid + 1];
            int h2 = s_hist[4 * tid + 2], h3 = s_hist[4 * tid + 3];
            int s3 = h3, s2 = h2 + s3, s1 = h1 + s2, s0 = h0 + s1;
            int acc = s0;
            #pragma unroll
            for (int o = 1; o < 64; o <<= 1) {
                int t = __shfl_down(acc, o);
                if (tid + o < 64) acc += t;  // inclusive suffix over lane totals
            }
            int excl = acc - s0;
            int c0 = s0 + excl, c1 = s1 + excl, c2 = s2 + excl, c3 = s3 + excl;
            unsigned long long m = __ballot(c0 >= kk);
            int L = 63 - __clzll(m);         // highest lane containing the pivot
            if (tid == L) {
                int vi, cnext;
                if (c3 >= kk)      { vi = 3; cnext = excl; }
                else if (c2 >= kk) { vi = 2; cnext = c3; }
                else if (c1 >= kk) { vi = 1; cnext = c2; }
                else               { vi = 0; cnext = c1; }
                s_vk[0] = 4 * tid + vi;
                s_vk[1] = kk - cnext;
            }
        }
        __syncthreads();
        P |= ((unsigned)s_vk[0]) << shift;
        kk = s_vk[1];
        __syncthreads();                     // s_hist reused next round
    }

    const unsigned T = P;
    float sum = 0.f;
    int cgt = 0;
    #pragma unroll
    for (int j = 0; j < TK_KEYS; ++j) {
        if (key[j] > T) { sum += __uint_as_float(key[j]); cgt++; }
    }
    for (int o = 32; o > 0; o >>= 1) {
        sum += __shfl_down(sum, o);
        cgt += __shfl_down(cgt, o);
    }
    __shared__ float s_s[8];
    __shared__ int s_c[8];
    if ((tid & 63) == 0) { s_s[tid >> 6] = sum; s_c[tid >> 6] = cgt; }
    __syncthreads();
    if (tid == 0) {
        float tot = 0.f; int ctot = 0;
        for (int w = 0; w < 8; ++w) { tot += s_s[w]; ctot += s_c[w]; }
        float neg = tot + (float)(k - ctot) * __uint_as_float(T);
        atomicAdd(&accum[1], (double)neg);
        __threadfence();
        int prev = atomicAdd(done_cnt, 1);
        if (prev == BB - 1) {                // last block: finalize
            double a1 = atomicAdd(&accum[1], 0.0);  // posl + all neg
            int N = 0;
            double ll = 0.0;
            for (int i = 0; i < BB * NCHUNK; ++i) {
                N += num_pos_part[i];
                ll += (double)lloss_part[i];
            }
            out[0] = (float)((ll + a1) / (double)N);   // ALPHA = 1
        }
    }
}

extern "C" void kernel_launch(void* const* d_in, const int* in_sizes, int n_in,
                              void* d_out, int out_size, void* d_ws, size_t ws_size,
                              hipStream_t stream) {
    const float* loc_data  = (const float*)d_in[0];
    const float* conf_data = (const float*)d_in[1];
    const float* priors    = (const float*)d_in[2];
    const float* targets   = (const float*)d_in[3];

    char* ws = (char*)d_ws;
    // layout: [0,16) double accum[2] (accum[1] = posl + neg total);
    //         [16,20) done_cnt;
    //         [32,1056) int num_pos_part[64][4];
    //         [1056,2080) float lloss_part[64][4];
    //         [2560, +BB*PP) u8 conf_t; then float lcm[BB*PP]
    double* accum = (double*)ws;
    int* done_cnt = (int*)(ws + 16);
    int* num_pos_part = (int*)(ws + 32);
    float* lloss_part = (float*)(ws + 1056);
    unsigned char* conf_t = (unsigned char*)(ws + 2560);
    float* lcm = (float*)(ws + 2560 + (size_t)BB * PP);

    // no memset dispatch: partials are plain-stored; accum/done_cnt zeroed
    // inside k_match (stream-ordered before any reader).

    dim3 mg(NCHUNK, BB);
    k_match<<<mg, 256, 0, stream>>>(loc_data, priors, targets, conf_t,
                                    num_pos_part, lloss_part, done_cnt, accum);

    k_conf<<<(BB * PP) / 256, 256, 0, stream>>>(conf_data, conf_t, lcm, accum);

    k_topk<<<BB, TK_THREADS, 0, stream>>>(lcm, num_pos_part, lloss_part,
                                          accum, done_cnt, (float*)d_out);
}

// Round 6
// 350.800 us; speedup vs baseline: 1.0280x; 1.0280x over previous
//
#include <hip/hip_runtime.h>

#define BB 64
#define PP 8732
#define NOBJ 16
#define NC 81
#define THRESH 0.5f
#define NEGPOS 3
#define NCHUNK 32
#define CHUNK ((PP + NCHUNK - 1) / NCHUNK)   // 273; last chunk = 269

#define TK_THREADS 512
#define TK_KEYS 18            // 17*512 = 8704; threads 0..27 hold an 18th key

__device__ __forceinline__ float smooth_l1(float x) {
    float ax = fabsf(x);
    return (ax < 1.0f) ? 0.5f * x * x : ax - 0.5f;
}

// ---------- Kernel 1A: per-truth best prior, per-chunk partials ----------
// Grid (NCHUNK, BB) x 256 = 2048 blocks (~8/CU: occupancy is the match-path
// lever, R5 showed it is latency-bound at low TLP). Plain stores -> no
// zero-init. Chunk-0 blocks also zero num_pos/accum/done_cnt (stream-ordered
// before their readers).
__global__ __launch_bounds__(256) void k_matchA(
    const float* __restrict__ priors, const float* __restrict__ targets,
    unsigned long long* __restrict__ g_best_part,
    int* __restrict__ num_pos, double* __restrict__ accum,
    int* __restrict__ done_cnt)
{
    const int chunk = blockIdx.x;
    const int b = blockIdx.y;
    const int tid = threadIdx.x;

    __shared__ float s_tx1[NOBJ], s_ty1[NOBJ], s_tx2[NOBJ], s_ty2[NOBJ];
    __shared__ float s_area[NOBJ];
    __shared__ unsigned long long s_best[NOBJ];

    if (tid < NOBJ) {
        const float* t = targets + ((size_t)b * NOBJ + tid) * 5;
        float x1 = t[0], y1 = t[1], x2 = t[2], y2 = t[3];
        s_tx1[tid] = x1; s_ty1[tid] = y1; s_tx2[tid] = x2; s_ty2[tid] = y2;
        s_area[tid] = (x2 - x1) * (y2 - y1);
        s_best[tid] = 0ull;
    }
    if (chunk == 0 && tid == 0) {
        num_pos[b] = 0;
        if (b == 0) { accum[0] = 0.0; accum[1] = 0.0; done_cnt[0] = 0; }
    }
    __syncthreads();

    unsigned long long best[NOBJ];
    #pragma unroll
    for (int t = 0; t < NOBJ; ++t) best[t] = 0ull;

    const int p0 = chunk * CHUNK;
    int p1 = p0 + CHUNK; if (p1 > PP) p1 = PP;
    for (int p = p0 + tid; p < p1; p += 256) {
        float4 pr = ((const float4*)priors)[p];
        float px1 = pr.x - pr.z * 0.5f, py1 = pr.y - pr.w * 0.5f;
        float px2 = pr.x + pr.z * 0.5f, py2 = pr.y + pr.w * 0.5f;
        float pa = (px2 - px1) * (py2 - py1);
        unsigned revp = 0xFFFFFFFFu - (unsigned)p;   // tie -> smaller p wins
        #pragma unroll
        for (int t = 0; t < NOBJ; ++t) {
            float ix1 = fmaxf(s_tx1[t], px1), iy1 = fmaxf(s_ty1[t], py1);
            float ix2 = fminf(s_tx2[t], px2), iy2 = fminf(s_ty2[t], py2);
            float iw = fmaxf(ix2 - ix1, 0.f), ih = fmaxf(iy2 - iy1, 0.f);
            float inter = iw * ih;
            float iou = inter / (s_area[t] + pa - inter);
            unsigned long long key =
                ((unsigned long long)__float_as_uint(iou) << 32) | revp;
            if (key > best[t]) best[t] = key;
        }
    }
    #pragma unroll
    for (int t = 0; t < NOBJ; ++t) {
        unsigned long long v = best[t];
        for (int o = 32; o > 0; o >>= 1) {
            unsigned long long w = __shfl_down(v, o);
            if (w > v) v = w;
        }
        if ((tid & 63) == 0) atomicMax(&s_best[t], v);
    }
    __syncthreads();
    if (tid < NOBJ)
        g_best_part[((size_t)b * NOBJ + tid) * NCHUNK + chunk] = s_best[tid];
}

// ---------- Kernel 1B: per-prior match + loc loss + conf_t ----------
__global__ __launch_bounds__(256) void k_matchB(
    const float* __restrict__ loc_data, const float* __restrict__ priors,
    const float* __restrict__ targets,
    const unsigned long long* __restrict__ g_best_part,
    unsigned char* __restrict__ conf_t, int* __restrict__ num_pos,
    double* __restrict__ accum)
{
    const int chunk = blockIdx.x;
    const int b = blockIdx.y;
    const int tid = threadIdx.x;

    __shared__ float s_tx1[NOBJ], s_ty1[NOBJ], s_tx2[NOBJ], s_ty2[NOBJ];
    __shared__ float s_lab[NOBJ], s_area[NOBJ];
    __shared__ int s_bpi[NOBJ];

    if (tid < NOBJ) {
        const float* t = targets + ((size_t)b * NOBJ + tid) * 5;
        float x1 = t[0], y1 = t[1], x2 = t[2], y2 = t[3];
        s_tx1[tid] = x1; s_ty1[tid] = y1; s_tx2[tid] = x2; s_ty2[tid] = y2;
        s_lab[tid] = t[4];
        s_area[tid] = (x2 - x1) * (y2 - y1);
        const unsigned long long* part =
            g_best_part + ((size_t)b * NOBJ + tid) * NCHUNK;
        unsigned long long m = part[0];
        #pragma unroll
        for (int c = 1; c < NCHUNK; ++c)
            if (part[c] > m) m = part[c];
        s_bpi[tid] = (int)(0xFFFFFFFFu - (unsigned)(m & 0xFFFFFFFFull));
    }
    __syncthreads();

    int n_pos = 0;
    float lloss = 0.f;
    const int p0 = chunk * CHUNK;
    int p1 = p0 + CHUNK; if (p1 > PP) p1 = PP;
    for (int p = p0 + tid; p < p1; p += 256) {
        float4 pr = ((const float4*)priors)[p];
        float px1 = pr.x - pr.z * 0.5f, py1 = pr.y - pr.w * 0.5f;
        float px2 = pr.x + pr.z * 0.5f, py2 = pr.y + pr.w * 0.5f;
        float pa = (px2 - px1) * (py2 - py1);
        float bt_ov = -1.f;
        int bt_idx = 0;
        #pragma unroll
        for (int t = 0; t < NOBJ; ++t) {
            float ix1 = fmaxf(s_tx1[t], px1), iy1 = fmaxf(s_ty1[t], py1);
            float ix2 = fminf(s_tx2[t], px2), iy2 = fminf(s_ty2[t], py2);
            float iw = fmaxf(ix2 - ix1, 0.f), ih = fmaxf(iy2 - iy1, 0.f);
            float inter = iw * ih;
            float iou = inter / (s_area[t] + pa - inter);
            if (iou > bt_ov) { bt_ov = iou; bt_idx = t; }  // strict >: first-max
        }
        #pragma unroll
        for (int i = 0; i < NOBJ; ++i)           // last-wins scatter override
            if (s_bpi[i] == p) { bt_idx = i; bt_ov = 2.0f; }

        int c = (bt_ov < THRESH) ? 0 : ((int)s_lab[bt_idx] + 1);
        conf_t[(size_t)b * PP + p] = (unsigned char)c;

        if (c > 0) {
            n_pos++;
            float mx1 = s_tx1[bt_idx], my1 = s_ty1[bt_idx];
            float mx2 = s_tx2[bt_idx], my2 = s_ty2[bt_idx];
            float gcx = ((mx1 + mx2) * 0.5f - pr.x) / (0.1f * pr.z);
            float gcy = ((my1 + my2) * 0.5f - pr.y) / (0.1f * pr.w);
            float gw = logf((mx2 - mx1) / pr.z) / 0.2f;
            float gh = logf((my2 - my1) / pr.w) / 0.2f;
            float4 ld = ((const float4*)loc_data)[(size_t)b * PP + p];
            lloss += smooth_l1(ld.x - gcx) + smooth_l1(ld.y - gcy) +
                     smooth_l1(ld.z - gw) + smooth_l1(ld.w - gh);
        }
    }

    for (int o = 32; o > 0; o >>= 1) {
        n_pos += __shfl_down(n_pos, o);
        lloss += __shfl_down(lloss, o);
    }
    __shared__ int s_np[4];
    __shared__ float s_ll[4];
    int wave = tid >> 6, lane = tid & 63;
    if (lane == 0) { s_np[wave] = n_pos; s_ll[wave] = lloss; }
    __syncthreads();
    if (tid == 0) {
        atomicAdd(&num_pos[b], s_np[0] + s_np[1] + s_np[2] + s_np[3]);
        atomicAdd(&accum[0], (double)(s_ll[0] + s_ll[1] + s_ll[2] + s_ll[3]));
    }
}

// ---------- Kernel 2: conf loss, double-buffered LDS, octet-per-row ----------
// (byte-for-byte the verified kernel)
__global__ __launch_bounds__(256) void k_conf(
    const float* __restrict__ conf_data, const unsigned char* __restrict__ conf_t,
    float* __restrict__ lcm, double* __restrict__ accum)
{
    __shared__ float4 s_buf4[2][648];        // 2 x 32 rows x 81 floats
    const int tid = threadIdx.x;
    const int r = tid >> 3;                  // row in half-chunk (0..31)
    const int s = tid & 7;                   // octet segment (0..7)
    const int seg_start = s * 10;
    const int seg_len = (s == 7) ? 11 : 10;  // 7*10 + 11 = 81
    const int base_row = blockIdx.x * 256;   // 2183*256 == BB*PP exactly
    const float4* g4base = (const float4*)conf_data;

    float4 t0, t1, t2;
    {
        const float4* g4 = g4base + (size_t)base_row * NC / 4;
        t0 = g4[tid]; t1 = g4[tid + 256];
        if (tid < 136) t2 = g4[tid + 512];
    }

    float posl = 0.f;
    for (int h = 0; h < 8; ++h) {
        float4* buf = s_buf4[h & 1];
        buf[tid] = t0; buf[tid + 256] = t1;
        if (tid < 136) buf[tid + 512] = t2;
        if (h + 1 < 8) {                     // issue next loads (latency hidden)
            const float4* g4 = g4base + (size_t)(base_row + (h + 1) * 32) * NC / 4;
            t0 = g4[tid]; t1 = g4[tid + 256];
            if (tid < 136) t2 = g4[tid + 512];
        }
        __syncthreads();                     // single barrier per half-chunk

        const float* myrow = (const float*)buf + r * NC;
        float v[11];
        #pragma unroll
        for (int j = 0; j < 11; ++j) v[j] = myrow[seg_start + j];

        float m = -1e30f;
        #pragma unroll
        for (int j = 0; j < 11; ++j) m = fmaxf(m, (j < seg_len) ? v[j] : -1e30f);
        m = fmaxf(m, __shfl_xor(m, 1));
        m = fmaxf(m, __shfl_xor(m, 2));
        m = fmaxf(m, __shfl_xor(m, 4));
        float e = 0.f;
        #pragma unroll
        for (int j = 0; j < 11; ++j) e += (j < seg_len) ? __expf(v[j] - m) : 0.f;
        e += __shfl_xor(e, 1);
        e += __shfl_xor(e, 2);
        e += __shfl_xor(e, 4);

        if (s == 0) {
            int row = base_row + h * 32 + r;
            int c = (int)conf_t[row];
            float lse = m + __logf(e);
            float lc = lse - myrow[c];
            bool pos = c > 0;
            lcm[row] = pos ? 0.f : lc;
            if (pos) posl += lc;
        }
    }
    for (int o = 32; o > 0; o >>= 1) posl += __shfl_down(posl, o);
    __shared__ float s_w[4];
    if ((tid & 63) == 0) s_w[tid >> 6] = posl;
    __syncthreads();
    if (tid == 0)
        atomicAdd(&accum[1], (double)(s_w[0] + s_w[1] + s_w[2] + s_w[3]));
}

// ---------- Kernel 3: per-batch top-k via radix-256 select + finalize ----------
// (verified radix-256 structure)
__global__ __launch_bounds__(TK_THREADS) void k_topk(
    const float* __restrict__ lcm, const int* __restrict__ num_pos,
    double* __restrict__ accum, int* __restrict__ done_cnt,
    float* __restrict__ out)
{
    const int b = blockIdx.x, tid = threadIdx.x;
    unsigned key[TK_KEYS];
    #pragma unroll
    for (int j = 0; j < TK_KEYS; ++j) {
        int i = tid + j * TK_THREADS;
        key[j] = (i < PP) ? __float_as_uint(lcm[(size_t)b * PP + i]) : 0u;
    }
    __shared__ int s_hist[256];
    __shared__ int s_vk[2];                  // {selected byte, next kk}
    int k = NEGPOS * num_pos[b];
    if (k > PP - 1) k = PP - 1;

    unsigned P = 0;
    int kk = k;
    #pragma unroll
    for (int rd = 0; rd < 4; ++rd) {
        const int shift = 24 - 8 * rd;
        if (tid < 256) s_hist[tid] = 0;
        __syncthreads();
        const unsigned hi_mask = (rd == 0) ? 0u : (0xFFFFFFFFu << (shift + 8));
        #pragma unroll
        for (int j = 0; j < TK_KEYS; ++j) {
            int i = tid + j * TK_THREADS;
            if (i < PP && (((key[j] ^ P) & hi_mask) == 0u))
                atomicAdd(&s_hist[(key[j] >> shift) & 255], 1);
        }
        __syncthreads();
        if (tid < 64) {                      // wave 0: suffix-scan 256 bins
            int h0 = s_hist[4 * tid + 0], h1 = s_hist[4 * tid + 1];
            int h2 = s_hist[4 * tid + 2], h3 = s_hist[4 * tid + 3];
            int s3 = h3, s2 = h2 + s3, s1 = h1 + s2, s0 = h0 + s1;
            int acc = s0;
            #pragma unroll
            for (int o = 1; o < 64; o <<= 1) {
                int t = __shfl_down(acc, o);
                if (tid + o < 64) acc += t;  // inclusive suffix over lane totals
            }
            int excl = acc - s0;
            int c0 = s0 + excl, c1 = s1 + excl, c2 = s2 + excl, c3 = s3 + excl;
            unsigned long long m = __ballot(c0 >= kk);
            int L = 63 - __clzll(m);         // highest lane containing the pivot
            if (tid == L) {
                int vi, cnext;
                if (c3 >= kk)      { vi = 3; cnext = excl; }
                else if (c2 >= kk) { vi = 2; cnext = c3; }
                else if (c1 >= kk) { vi = 1; cnext = c2; }
                else               { vi = 0; cnext = c1; }
                s_vk[0] = 4 * tid + vi;
                s_vk[1] = kk - cnext;
            }
        }
        __syncthreads();
        P |= ((unsigned)s_vk[0]) << shift;
        kk = s_vk[1];
        __syncthreads();                     // s_hist reused next round
    }

    const unsigned T = P;
    float sum = 0.f;
    int cgt = 0;
    #pragma unroll
    for (int j = 0; j < TK_KEYS; ++j) {
        if (key[j] > T) { sum += __uint_as_float(key[j]); cgt++; }
    }
    for (int o = 32; o > 0; o >>= 1) {
        sum += __shfl_down(sum, o);
        cgt += __shfl_down(cgt, o);
    }
    __shared__ float s_s[8];
    __shared__ int s_c[8];
    if ((tid & 63) == 0) { s_s[tid >> 6] = sum; s_c[tid >> 6] = cgt; }
    __syncthreads();
    if (tid == 0) {
        float tot = 0.f; int ctot = 0;
        for (int w = 0; w < 8; ++w) { tot += s_s[w]; ctot += s_c[w]; }
        float neg = tot + (float)(k - ctot) * __uint_as_float(T);
        atomicAdd(&accum[1], (double)neg);
        __threadfence();
        int prev = atomicAdd(done_cnt, 1);
        if (prev == BB - 1) {                // last block: finalize
            double a0 = atomicAdd(&accum[0], 0.0);
            double a1 = atomicAdd(&accum[1], 0.0);
            int N = 0;
            for (int bb = 0; bb < BB; ++bb) N += num_pos[bb];
            out[0] = (float)((a0 + a1) / (double)N);   // ALPHA = 1
        }
    }
}

extern "C" void kernel_launch(void* const* d_in, const int* in_sizes, int n_in,
                              void* d_out, int out_size, void* d_ws, size_t ws_size,
                              hipStream_t stream) {
    const float* loc_data  = (const float*)d_in[0];
    const float* conf_data = (const float*)d_in[1];
    const float* priors    = (const float*)d_in[2];
    const float* targets   = (const float*)d_in[3];

    char* ws = (char*)d_ws;
    // layout: [0,16) double accum[2]; [16,20) done_cnt; [32,288) int num_pos[64];
    //         [512, 512+64*16*32*8=262656) u64 g_best_part[b][t][chunk];
    //         [262656, +BB*PP) u8 conf_t; then float lcm[BB*PP] (4-aligned)
    double* accum = (double*)ws;
    int* done_cnt = (int*)(ws + 16);
    int* num_pos = (int*)(ws + 32);
    unsigned long long* g_best_part = (unsigned long long*)(ws + 512);
    unsigned char* conf_t = (unsigned char*)(ws + 262656);
    float* lcm = (float*)(ws + 262656 + (size_t)BB * PP);

    // no memset dispatch: g_best_part is plain-stored (per-chunk partials),
    // num_pos/accum/done_cnt zeroed inside k_matchA (stream-ordered before
    // any reader), conf_t/lcm fully overwritten every launch.

    dim3 mg(NCHUNK, BB);
    k_matchA<<<mg, 256, 0, stream>>>(priors, targets, g_best_part,
                                     num_pos, accum, done_cnt);
    k_matchB<<<mg, 256, 0, stream>>>(loc_data, priors, targets, g_best_part,
                                     conf_t, num_pos, accum);

    k_conf<<<(BB * PP) / 256, 256, 0, stream>>>(conf_data, conf_t, lcm, accum);

    k_topk<<<BB, TK_THREADS, 0, stream>>>(lcm, num_pos, accum, done_cnt,
                                          (float*)d_out);
}

// Round 7
// 296.580 us; speedup vs baseline: 1.2160x; 1.1828x over previous
//
#include <hip/hip_runtime.h>

#define BB 64
#define PP 8732
#define NOBJ 16
#define NC 81
#define THRESH 0.5f
#define NEGPOS 3
#define NCHUNK 4
#define CHUNK (PP / NCHUNK)   // 2183
#define NBLK 2183             // fused-conf blocks: 2183*256 == BB*PP

#define TK_THREADS 512
#define TK_KEYS 18            // 17*512 = 8704; threads 0..27 hold an 18th key

__device__ __forceinline__ float smooth_l1(float x) {
    float ax = fabsf(x);
    return (ax < 1.0f) ? 0.5f * x * x : ax - 0.5f;
}

// ---------- Kernel 1: per-truth best prior, per-chunk partials ----------
// (R2-verified structure, NCHUNK=4.) Plain stores -> no zero-init.
// One block zeroes the 3 cross-dispatch scalars (stream-ordered).
__global__ __launch_bounds__(256) void k_matchA(
    const float* __restrict__ priors, const float* __restrict__ targets,
    unsigned long long* __restrict__ g_best_part,
    double* __restrict__ accum, int* __restrict__ nsum,
    int* __restrict__ done_cnt)
{
    const int chunk = blockIdx.x;
    const int b = blockIdx.y;
    const int tid = threadIdx.x;

    __shared__ float s_tx1[NOBJ], s_ty1[NOBJ], s_tx2[NOBJ], s_ty2[NOBJ];
    __shared__ float s_area[NOBJ];
    __shared__ unsigned long long s_best[NOBJ];

    if (tid < NOBJ) {
        const float* t = targets + ((size_t)b * NOBJ + tid) * 5;
        float x1 = t[0], y1 = t[1], x2 = t[2], y2 = t[3];
        s_tx1[tid] = x1; s_ty1[tid] = y1; s_tx2[tid] = x2; s_ty2[tid] = y2;
        s_area[tid] = (x2 - x1) * (y2 - y1);
        s_best[tid] = 0ull;
    }
    if (chunk == 0 && b == 0 && tid == 0) {
        accum[0] = 0.0; nsum[0] = 0; done_cnt[0] = 0;
    }
    __syncthreads();

    unsigned long long best[NOBJ];
    #pragma unroll
    for (int t = 0; t < NOBJ; ++t) best[t] = 0ull;

    const int p0 = chunk * CHUNK, p1 = p0 + CHUNK;
    for (int p = p0 + tid; p < p1; p += 256) {
        float4 pr = ((const float4*)priors)[p];
        float px1 = pr.x - pr.z * 0.5f, py1 = pr.y - pr.w * 0.5f;
        float px2 = pr.x + pr.z * 0.5f, py2 = pr.y + pr.w * 0.5f;
        float pa = (px2 - px1) * (py2 - py1);
        unsigned revp = 0xFFFFFFFFu - (unsigned)p;   // tie -> smaller p wins
        #pragma unroll
        for (int t = 0; t < NOBJ; ++t) {
            float ix1 = fmaxf(s_tx1[t], px1), iy1 = fmaxf(s_ty1[t], py1);
            float ix2 = fminf(s_tx2[t], px2), iy2 = fminf(s_ty2[t], py2);
            float iw = fmaxf(ix2 - ix1, 0.f), ih = fmaxf(iy2 - iy1, 0.f);
            float inter = iw * ih;
            float iou = inter / (s_area[t] + pa - inter);
            unsigned long long key =
                ((unsigned long long)__float_as_uint(iou) << 32) | revp;
            if (key > best[t]) best[t] = key;
        }
    }
    #pragma unroll
    for (int t = 0; t < NOBJ; ++t) {
        unsigned long long v = best[t];
        for (int o = 32; o > 0; o >>= 1) {
            unsigned long long w = __shfl_down(v, o);
            if (w > v) v = w;
        }
        if ((tid & 63) == 0) atomicMax(&s_best[t], v);
    }
    __syncthreads();
    if (tid < NOBJ)
        g_best_part[((size_t)b * NOBJ + tid) * NCHUNK + chunk] = s_best[tid];
}

// ---------- Kernel 2: fused per-prior match + conf loss ----------
// 2183 blocks x 256. Match phase: one row (= one batch,prior pair) per
// thread at full occupancy -> c into LDS + loc loss per thread; matchB's
// dispatch, its conf_t round-trip, and its same-address atomics disappear.
// Conf phase: verified double-buffered LDS loop, c read from LDS.
// Partials (llp = loc+posl, np per batch segment) plain-stored per block.
__global__ __launch_bounds__(256) void k_conf_fused(
    const float* __restrict__ loc_data, const float* __restrict__ conf_data,
    const float* __restrict__ priors, const float* __restrict__ targets,
    const unsigned long long* __restrict__ g_best_part,
    float* __restrict__ lcm, float* __restrict__ llp_part,
    int2* __restrict__ np_part)
{
    __shared__ float4 s_buf4[2][648];        // 2 x 32 rows x 81 floats
    __shared__ float s_tx1[2][NOBJ], s_ty1[2][NOBJ];
    __shared__ float s_tx2[2][NOBJ], s_ty2[2][NOBJ];
    __shared__ float s_lab[2][NOBJ], s_area[2][NOBJ];
    __shared__ int s_bpi[2][NOBJ];
    __shared__ int s_conf[256];
    const int tid = threadIdx.x;
    const int base_row = blockIdx.x * 256;
    const int b0 = base_row / PP;
    int split = (b0 + 1) * PP - base_row;    // rows of batch b0 in this block
    if (split > 256) split = 256;
    const bool two = (split < 256);          // block spans two batches

    // truths + best-prior-idx for (up to) two batches
    if (tid < 32) {
        int bt = tid >> 4, t = tid & 15;
        if (bt == 0 || two) {
            int gb = b0 + bt;
            const float* tp = targets + ((size_t)gb * NOBJ + t) * 5;
            float x1 = tp[0], y1 = tp[1], x2 = tp[2], y2 = tp[3];
            s_tx1[bt][t] = x1; s_ty1[bt][t] = y1;
            s_tx2[bt][t] = x2; s_ty2[bt][t] = y2;
            s_lab[bt][t] = tp[4];
            s_area[bt][t] = (x2 - x1) * (y2 - y1);
            const unsigned long long* part =
                g_best_part + ((size_t)gb * NOBJ + t) * NCHUNK;
            unsigned long long m = part[0];
            #pragma unroll
            for (int c = 1; c < NCHUNK; ++c)
                if (part[c] > m) m = part[c];
            s_bpi[bt][t] = (int)(0xFFFFFFFFu - (unsigned)(m & 0xFFFFFFFFull));
        }
    }

    // issue initial conf loads (latency hides under the match phase)
    const float4* g4base = (const float4*)conf_data;
    float4 t0, t1, t2;
    {
        const float4* g4 = g4base + (size_t)base_row * NC / 4;
        t0 = g4[tid]; t1 = g4[tid + 256];
        if (tid < 136) t2 = g4[tid + 512];
    }
    __syncthreads();

    // ---- match phase: one row per thread, full wave utilization ----
    const int seg = (tid < split) ? 0 : 1;
    const int row = base_row + tid;
    const int p = row - (b0 + seg) * PP;
    float llp = 0.f;
    int np0 = 0, np1 = 0;
    {
        float4 pr = ((const float4*)priors)[p];
        float px1 = pr.x - pr.z * 0.5f, py1 = pr.y - pr.w * 0.5f;
        float px2 = pr.x + pr.z * 0.5f, py2 = pr.y + pr.w * 0.5f;
        float pa = (px2 - px1) * (py2 - py1);
        float bt_ov = -1.f;
        int bt_idx = 0;
        #pragma unroll
        for (int t = 0; t < NOBJ; ++t) {
            float ix1 = fmaxf(s_tx1[seg][t], px1), iy1 = fmaxf(s_ty1[seg][t], py1);
            float ix2 = fminf(s_tx2[seg][t], px2), iy2 = fminf(s_ty2[seg][t], py2);
            float iw = fmaxf(ix2 - ix1, 0.f), ih = fmaxf(iy2 - iy1, 0.f);
            float inter = iw * ih;
            float iou = inter / (s_area[seg][t] + pa - inter);
            if (iou > bt_ov) { bt_ov = iou; bt_idx = t; }  // strict >: first-max
        }
        #pragma unroll
        for (int i = 0; i < NOBJ; ++i)           // last-wins scatter override
            if (s_bpi[seg][i] == p) { bt_idx = i; bt_ov = 2.0f; }

        int c = (bt_ov < THRESH) ? 0 : ((int)s_lab[seg][bt_idx] + 1);
        s_conf[tid] = c;

        if (c > 0) {
            if (seg == 0) np0 = 1; else np1 = 1;
            float mx1 = s_tx1[seg][bt_idx], my1 = s_ty1[seg][bt_idx];
            float mx2 = s_tx2[seg][bt_idx], my2 = s_ty2[seg][bt_idx];
            float gcx = ((mx1 + mx2) * 0.5f - pr.x) / (0.1f * pr.z);
            float gcy = ((my1 + my2) * 0.5f - pr.y) / (0.1f * pr.w);
            float gw = logf((mx2 - mx1) / pr.z) / 0.2f;
            float gh = logf((my2 - my1) / pr.w) / 0.2f;
            float4 ld = ((const float4*)loc_data)[row];
            llp += smooth_l1(ld.x - gcx) + smooth_l1(ld.y - gcy) +
                   smooth_l1(ld.z - gw) + smooth_l1(ld.w - gh);
        }
    }
    __syncthreads();                         // s_conf ready

    // ---- conf phase: verified double-buffered loop ----
    const int r = tid >> 3;                  // row in half-chunk (0..31)
    const int s = tid & 7;                   // octet segment (0..7)
    const int seg_start = s * 10;
    const int seg_len = (s == 7) ? 11 : 10;  // 7*10 + 11 = 81

    for (int h = 0; h < 8; ++h) {
        float4* buf = s_buf4[h & 1];
        buf[tid] = t0; buf[tid + 256] = t1;
        if (tid < 136) buf[tid + 512] = t2;
        if (h + 1 < 8) {                     // issue next loads (latency hidden)
            const float4* g4 = g4base + (size_t)(base_row + (h + 1) * 32) * NC / 4;
            t0 = g4[tid]; t1 = g4[tid + 256];
            if (tid < 136) t2 = g4[tid + 512];
        }
        __syncthreads();                     // single barrier per half-chunk

        const float* myrow = (const float*)buf + r * NC;
        float v[11];
        #pragma unroll
        for (int j = 0; j < 11; ++j) v[j] = myrow[seg_start + j];

        float m = -1e30f;
        #pragma unroll
        for (int j = 0; j < 11; ++j) m = fmaxf(m, (j < seg_len) ? v[j] : -1e30f);
        m = fmaxf(m, __shfl_xor(m, 1));
        m = fmaxf(m, __shfl_xor(m, 2));
        m = fmaxf(m, __shfl_xor(m, 4));
        float e = 0.f;
        #pragma unroll
        for (int j = 0; j < 11; ++j) e += (j < seg_len) ? __expf(v[j] - m) : 0.f;
        e += __shfl_xor(e, 1);
        e += __shfl_xor(e, 2);
        e += __shfl_xor(e, 4);

        if (s == 0) {
            int idx = h * 32 + r;
            int c = s_conf[idx];
            float lse = m + __logf(e);
            float lc = lse - myrow[c];
            bool pos = c > 0;
            lcm[base_row + idx] = pos ? 0.f : lc;
            if (pos) llp += lc;              // positive conf loss joins loc loss
        }
    }

    // ---- block reduce: llp (float), np0, np1 -> plain-store partials ----
    for (int o = 32; o > 0; o >>= 1) {
        llp += __shfl_down(llp, o);
        np0 += __shfl_down(np0, o);
        np1 += __shfl_down(np1, o);
    }
    __shared__ float s_l[4];
    __shared__ int s_n0[4], s_n1[4];
    if ((tid & 63) == 0) {
        s_l[tid >> 6] = llp; s_n0[tid >> 6] = np0; s_n1[tid >> 6] = np1;
    }
    __syncthreads();
    if (tid == 0) {
        llp_part[blockIdx.x] = s_l[0] + s_l[1] + s_l[2] + s_l[3];
        np_part[blockIdx.x] = make_int2(s_n0[0] + s_n0[1] + s_n0[2] + s_n0[3],
                                        s_n1[0] + s_n1[1] + s_n1[2] + s_n1[3]);
    }
}

// ---------- Kernel 3: per-batch top-k via radix-256 select + finalize ----------
// np_b assembled from the fused kernel's per-block segment partials.
// Cross-block same-dispatch state only through device-scope atomics
// (accum/nsum/done_cnt) -- the verified pattern.
__global__ __launch_bounds__(TK_THREADS) void k_topk(
    const float* __restrict__ lcm, const int2* __restrict__ np_part,
    const float* __restrict__ llp_part,
    double* __restrict__ accum, int* __restrict__ nsum,
    int* __restrict__ done_cnt, float* __restrict__ out)
{
    const int b = blockIdx.x, tid = threadIdx.x;

    // ---- np_b from block segment partials (<=36 covering blocks) ----
    __shared__ int s_npb;
    {
        int gs = (b * PP) >> 8;
        int ge = ((b + 1) * PP - 1) >> 8;
        int cnt = ge - gs + 1;
        int mynp = 0;
        if (tid < cnt) {
            int g = gs + tid;
            int2 e = np_part[g];
            int bg0 = (g << 8) / PP;
            mynp = (bg0 == b) ? e.x : e.y;   // segment belonging to batch b
        }
        if (tid < 64) {
            for (int o = 32; o > 0; o >>= 1) mynp += __shfl_down(mynp, o);
            if (tid == 0) s_npb = mynp;
        }
    }

    unsigned key[TK_KEYS];
    #pragma unroll
    for (int j = 0; j < TK_KEYS; ++j) {
        int i = tid + j * TK_THREADS;
        key[j] = (i < PP) ? __float_as_uint(lcm[(size_t)b * PP + i]) : 0u;
    }
    __shared__ int s_hist[256];
    __shared__ int s_vk[2];                  // {selected byte, next kk}
    __syncthreads();
    const int np = s_npb;
    int k = NEGPOS * np;
    if (k > PP - 1) k = PP - 1;

    unsigned P = 0;
    int kk = k;
    #pragma unroll
    for (int rd = 0; rd < 4; ++rd) {
        const int shift = 24 - 8 * rd;
        if (tid < 256) s_hist[tid] = 0;
        __syncthreads();
        const unsigned hi_mask = (rd == 0) ? 0u : (0xFFFFFFFFu << (shift + 8));
        #pragma unroll
        for (int j = 0; j < TK_KEYS; ++j) {
            int i = tid + j * TK_THREADS;
            if (i < PP && (((key[j] ^ P) & hi_mask) == 0u))
                atomicAdd(&s_hist[(key[j] >> shift) & 255], 1);
        }
        __syncthreads();
        if (tid < 64) {                      // wave 0: suffix-scan 256 bins
            int h0 = s_hist[4 * tid + 0], h1 = s_hist[4 * tid + 1];
            int h2 = s_hist[4 * tid + 2], h3 = s_hist[4 * tid + 3];
            int s3 = h3, s2 = h2 + s3, s1 = h1 + s2, s0 = h0 + s1;
            int acc = s0;
            #pragma unroll
            for (int o = 1; o < 64; o <<= 1) {
                int t = __shfl_down(acc, o);
                if (tid + o < 64) acc += t;  // inclusive suffix over lane totals
            }
            int excl = acc - s0;
            int c0 = s0 + excl, c1 = s1 + excl, c2 = s2 + excl, c3 = s3 + excl;
            unsigned long long m = __ballot(c0 >= kk);
            int L = 63 - __clzll(m);         // highest lane containing the pivot
            if (tid == L) {
                int vi, cnext;
                if (c3 >= kk)      { vi = 3; cnext = excl; }
                else if (c2 >= kk) { vi = 2; cnext = c3; }
                else if (c1 >= kk) { vi = 1; cnext = c2; }
                else               { vi = 0; cnext = c1; }
                s_vk[0] = 4 * tid + vi;
                s_vk[1] = kk - cnext;
            }
        }
        __syncthreads();
        P |= ((unsigned)s_vk[0]) << shift;
        kk = s_vk[1];
        __syncthreads();                     // s_hist reused next round
    }

    const unsigned T = P;
    float sum = 0.f;
    int cgt = 0;
    #pragma unroll
    for (int j = 0; j < TK_KEYS; ++j) {
        if (key[j] > T) { sum += __uint_as_float(key[j]); cgt++; }
    }
    for (int o = 32; o > 0; o >>= 1) {
        sum += __shfl_down(sum, o);
        cgt += __shfl_down(cgt, o);
    }
    __shared__ float s_s[8];
    __shared__ int s_c[8];
    __shared__ int s_last;
    if ((tid & 63) == 0) { s_s[tid >> 6] = sum; s_c[tid >> 6] = cgt; }
    __syncthreads();
    if (tid == 0) {
        float tot = 0.f; int ctot = 0;
        for (int w = 0; w < 8; ++w) { tot += s_s[w]; ctot += s_c[w]; }
        float neg = tot + (float)(k - ctot) * __uint_as_float(T);
        atomicAdd(&accum[0], (double)neg);
        atomicAdd(nsum, np);
        __threadfence();
        s_last = (atomicAdd(done_cnt, 1) == BB - 1) ? 1 : 0;
    }
    __syncthreads();

    if (s_last) {                            // last block: finalize
        double acc = 0.0;
        for (int i = tid; i < NBLK; i += TK_THREADS)
            acc += (double)llp_part[i];      // cross-dispatch data: plain OK
        for (int o = 32; o > 0; o >>= 1) acc += __shfl_down(acc, o);
        __shared__ double s_d[8];
        if ((tid & 63) == 0) s_d[tid >> 6] = acc;
        __syncthreads();
        if (tid == 0) {
            double llp_tot = 0.0;
            for (int w = 0; w < 8; ++w) llp_tot += s_d[w];
            double neg_tot = atomicAdd(&accum[0], 0.0);
            int N = atomicAdd(nsum, 0);
            out[0] = (float)((llp_tot + neg_tot) / (double)N);   // ALPHA = 1
        }
    }
}

extern "C" void kernel_launch(void* const* d_in, const int* in_sizes, int n_in,
                              void* d_out, int out_size, void* d_ws, size_t ws_size,
                              hipStream_t stream) {
    const float* loc_data  = (const float*)d_in[0];
    const float* conf_data = (const float*)d_in[1];
    const float* priors    = (const float*)d_in[2];
    const float* targets   = (const float*)d_in[3];

    char* ws = (char*)d_ws;
    // layout: [0,8) double accum[1]; [8,12) int nsum; [12,16) int done_cnt;
    //         [512, 512+64*16*4*8=33280) u64 g_best_part[b][t][chunk];
    //         [33280, +NBLK*4) float llp_part; [42016, +NBLK*8) int2 np_part;
    //         [59488, +BB*PP*4) float lcm
    double* accum = (double*)ws;
    int* nsum = (int*)(ws + 8);
    int* done_cnt = (int*)(ws + 12);
    unsigned long long* g_best_part = (unsigned long long*)(ws + 512);
    float* llp_part = (float*)(ws + 33280);
    int2* np_part = (int2*)(ws + 42016);
    float* lcm = (float*)(ws + 59488);

    // no memset dispatch: all partials plain-stored and fully overwritten;
    // accum/nsum/done_cnt zeroed inside k_matchA (stream-ordered).

    dim3 mg(NCHUNK, BB);
    k_matchA<<<mg, 256, 0, stream>>>(priors, targets, g_best_part,
                                     accum, nsum, done_cnt);

    k_conf_fused<<<NBLK, 256, 0, stream>>>(loc_data, conf_data, priors, targets,
                                           g_best_part, lcm, llp_part, np_part);

    k_topk<<<BB, TK_THREADS, 0, stream>>>(lcm, np_part, llp_part,
                                          accum, nsum, done_cnt, (float*)d_out);
}